// Round 2
// baseline (2016.346 us; speedup 1.0000x reference)
//
#include <hip/hip_runtime.h>
#include <stdint.h>

#define VOCAB 52000
#define EMB 768
#define H3 2304
#define CLS_ID 101

typedef short bf16x8 __attribute__((ext_vector_type(8)));   // 8 bf16 bit patterns
typedef float f32x4 __attribute__((ext_vector_type(4)));
typedef unsigned int u32x4 __attribute__((ext_vector_type(4)));

// RNE float->bf16
__device__ __forceinline__ unsigned short f2bf(float f) {
    union { float f; unsigned u; } v; v.f = f;
    unsigned r = v.u + 0x7FFFu + ((v.u >> 16) & 1u);
    return (unsigned short)(r >> 16);
}

// 2-bit granule swizzle for 64B LDS rows (16B granules): 2-way max = free
__device__ __forceinline__ int swz4(int row) { return (row ^ (row >> 2)) & 3; }

__device__ __forceinline__ void gload_lds16(const void* gsrc, void* ldst) {
    __builtin_amdgcn_global_load_lds(
        (const __attribute__((address_space(1))) unsigned int*)gsrc,
        (__attribute__((address_space(3))) unsigned int*)ldst, 16, 0, 0);
}

// coherent (IC-level) 4B store: bypasses per-XCD L2 (sc0 sc1)
__device__ __forceinline__ void ic_store(unsigned* p, unsigned v) {
    asm volatile("global_store_dword %0, %1, off sc0 sc1" :: "v"(p), "v"(v) : "memory");
}

// poll 12 tagged h-units (3x16B at p, p+1KB, p+2KB) until all tags == t; bounded.
__device__ __forceinline__ void pollh(const unsigned* p, unsigned t,
                                      float4& h0, float4& h1, float4& h2) {
    u32x4 a, b, c;
    int guard = 0;
    for (;;) {
        asm volatile(
            "global_load_dwordx4 %0, %3, off sc0 sc1\n\t"
            "global_load_dwordx4 %1, %3, off offset:1024 sc0 sc1\n\t"
            "global_load_dwordx4 %2, %3, off offset:2048 sc0 sc1\n\t"
            "s_waitcnt vmcnt(0)"
            : "=&v"(a), "=&v"(b), "=&v"(c)
            : "v"(p) : "memory");
        unsigned bad = ((a.x ^ t) | (a.y ^ t) | (a.z ^ t) | (a.w ^ t)
                      | (b.x ^ t) | (b.y ^ t) | (b.z ^ t) | (b.w ^ t)
                      | (c.x ^ t) | (c.y ^ t) | (c.z ^ t) | (c.w ^ t)) & 0xFFFFu;
        if (bad == 0u) break;
        if (++guard > 1000) break;   // bounded: never hang the container
    }
    h0.x = __uint_as_float(a.x & 0xFFFF0000u); h0.y = __uint_as_float(a.y & 0xFFFF0000u);
    h0.z = __uint_as_float(a.z & 0xFFFF0000u); h0.w = __uint_as_float(a.w & 0xFFFF0000u);
    h1.x = __uint_as_float(b.x & 0xFFFF0000u); h1.y = __uint_as_float(b.y & 0xFFFF0000u);
    h1.z = __uint_as_float(b.z & 0xFFFF0000u); h1.w = __uint_as_float(b.w & 0xFFFF0000u);
    h2.x = __uint_as_float(c.x & 0xFFFF0000u); h2.y = __uint_as_float(c.y & 0xFFFF0000u);
    h2.z = __uint_as_float(c.z & 0xFFFF0000u); h2.w = __uint_as_float(c.w & 0xFFFF0000u);
}

// ---------------- prep: hub row 0 = tagged enc_hs (tag 0); zero bf16 pad rows ----------------
__global__ void prep_kernel(const float* __restrict__ enc, unsigned* __restrict__ hub,
                            unsigned* __restrict__ pad0, unsigned* __restrict__ pad1) {
    int idx = blockIdx.x * blockDim.x + threadIdx.x;
    if (idx < 768) hub[idx] = ((unsigned)f2bf(enc[idx]) << 16);   // tag = 0
    if (idx < 384) { pad0[idx] = 0u; pad1[idx] = 0u; }            // row 511 of xemb / Hb
}

// ---------------- embedding gather -> bf16 A matrix [512][768] ----------------
__global__ void embed_kernel(const int* __restrict__ ids, const float* __restrict__ emb,
                             unsigned short* __restrict__ xemb) {
    int t = blockIdx.x;
    int token = (t == 0) ? CLS_ID : ids[t - 1];
    const float* src = emb + (size_t)token * EMB;
    unsigned short* dst = xemb + (size_t)t * EMB;
    for (int k = threadIdx.x; k < EMB; k += blockDim.x) dst[k] = f2bf(src[k]);
}

// ---------------- GEMM: C[512 x N] = A(bf16 [512][768]) * B(f32 [N][768])^T + bias ----------------
__launch_bounds__(512)
__global__ void gemm_kernel(const unsigned short* __restrict__ A, const float* __restrict__ B,
                            const float* __restrict__ bias, float* __restrict__ C,
                            int N, int Mvalid) {
    __shared__ __align__(16) unsigned short As[512 * 32];   // 32 KiB
    __shared__ __align__(16) unsigned short Bs[64 * 32];    // 4 KiB
    const int tid = threadIdx.x;
    const int lane = tid & 63;
    const int w = tid >> 6;
    const int lr = lane & 15, lg = lane >> 4;
    const int n0 = blockIdx.x * 64;

    f32x4 acc[4][4];
    #pragma unroll
    for (int i = 0; i < 4; ++i)
        #pragma unroll
        for (int jj = 0; jj < 4; ++jj)
            #pragma unroll
            for (int e = 0; e < 4; ++e) acc[i][jj][e] = 0.f;

    const int brow = tid >> 3, bseg = tid & 7;
    int bn = n0 + brow; if (bn >= N) bn = N - 1;
    const float* bsrc = B + (size_t)bn * EMB + bseg * 4;
    const int bbyte = brow * 64 + (((bseg >> 1) ^ swz4(brow)) * 16) + (bseg & 1) * 8;

    char* AsB = (char*)As;
    char* BsB = (char*)Bs;

    for (int kc = 0; kc < 24; ++kc) {
        const int k0 = kc * 32;
        #pragma unroll
        for (int is = 0; is < 4; ++is) {
            int g = is * 512 + tid;
            int row = g >> 2, gc = g & 3;
            const unsigned short* src = A + (size_t)row * EMB + k0 + ((gc ^ swz4(row)) * 8);
            gload_lds16(src, AsB + is * 8192 + (tid & ~63) * 16);
        }
        f32x4 bv = __builtin_nontemporal_load((const f32x4*)(bsrc + k0));  // B: zero reuse
        unsigned p0 = (unsigned)f2bf(bv[0]) | ((unsigned)f2bf(bv[1]) << 16);
        unsigned p1 = (unsigned)f2bf(bv[2]) | ((unsigned)f2bf(bv[3]) << 16);
        *(uint2*)(BsB + bbyte) = make_uint2(p0, p1);
        __syncthreads();

        bf16x8 af[4], bf[4];
        #pragma unroll
        for (int mf = 0; mf < 4; ++mf) {
            int row = w * 64 + mf * 16 + lr;
            af[mf] = *(const bf16x8*)(AsB + row * 64 + ((lg ^ swz4(row)) * 16));
        }
        #pragma unroll
        for (int nf = 0; nf < 4; ++nf) {
            int row = nf * 16 + lr;
            bf[nf] = *(const bf16x8*)(BsB + row * 64 + ((lg ^ swz4(row)) * 16));
        }
        #pragma unroll
        for (int mf = 0; mf < 4; ++mf)
            #pragma unroll
            for (int nf = 0; nf < 4; ++nf)
                acc[mf][nf] = __builtin_amdgcn_mfma_f32_16x16x32_bf16(af[mf], bf[nf], acc[mf][nf], 0, 0, 0);
        __syncthreads();
    }

    #pragma unroll
    for (int nf = 0; nf < 4; ++nf) {
        int n = n0 + nf * 16 + lr;
        float bb = bias[n < N ? n : N - 1];
        bool nok = n < N;
        #pragma unroll
        for (int mf = 0; mf < 4; ++mf) {
            #pragma unroll
            for (int reg = 0; reg < 4; ++reg) {
                int m = w * 64 + mf * 16 + lg * 4 + reg;
                if (nok && m < Mvalid) C[(size_t)m * N + n] = acc[mf][nf][reg] + bb;
            }
        }
    }
}

// ---------------- recurrence: 64 blocks, W_hh LDS-resident, tagged-word h broadcast ----------------
// block b owns h[12b..12b+12); wave w computes gates 3w..3w+2 (rows {j, 12+j, 24+j} local).
// No __syncthreads and no cross-wave LDS traffic inside the step loop.
__launch_bounds__(256)
__global__ void recur_kernel(const float* __restrict__ Whh, const float* __restrict__ bhh,
                             const float* __restrict__ enc, const float* __restrict__ xproj,
                             unsigned* __restrict__ hub, unsigned short* __restrict__ Hb,
                             int L) {
    __shared__ __align__(16) float Wl[36 * 768];   // 110.6 KiB -> 1 block/CU
    const int b = blockIdx.x, tid = threadIdx.x;
    const int lane = tid & 63, w = tid >> 6;

    {   // stage this block's 36 W_hh rows; local row r = sec*12 + j
        const f32x4* src = (const f32x4*)Whh;
        f32x4* dst = (f32x4*)Wl;
        for (int idx = tid; idx < 36 * 192; idx += 256) {
            int r = idx / 192, seg = idx - r * 192;
            int sec = r / 12, j = r - sec * 12;
            int gr = sec * 768 + b * 12 + j;
            dst[idx] = src[(size_t)gr * 192 + seg];
        }
    }
    const int j = 3 * w + lane;          // gate index when lane < 3
    float blr = 0.f, blz = 0.f, bln = 0.f, myh = 0.f;
    if (lane < 3) {
        blr = bhh[b * 12 + j];
        blz = bhh[768 + b * 12 + j];
        bln = bhh[1536 + b * 12 + j];
        myh = enc[b * 12 + j];           // own h^0 kept in f32
    }
    __syncthreads();                     // Wl ready

    float4 hv0, hv1, hv2;                // h[4*lane + {0,256,512} + 0..3] as f32 (from bf16)
    pollh(hub + 4 * lane, 0u, hv0, hv1, hv2);   // h^0 (prep wrote it; immediate)

    for (int s = 0; s < L; ++s) {
        // x_proj prefetch (depends only on s; hidden under matvec)
        float xpr = 0.f, xpz = 0.f, xpn = 0.f;
        if (lane < 3) {
            const float* xp = xproj + (size_t)s * H3 + b * 12 + j;
            xpr = xp[0]; xpz = xp[768]; xpn = xp[1536];
        }
        // matvec: 9 rows/wave, 12 k-values per lane, conflict-free b128 LDS reads
        float part[9];
        #pragma unroll
        for (int q = 0; q < 9; ++q) {
            const int g = q / 3, sec = q % 3;
            const int row = sec * 12 + 3 * w + g;
            const f32x4* wp = (const f32x4*)(Wl + row * 768);
            f32x4 a = wp[lane], c = wp[lane + 64], e = wp[lane + 128];
            part[q] = a[0]*hv0.x + a[1]*hv0.y + a[2]*hv0.z + a[3]*hv0.w
                    + c[0]*hv1.x + c[1]*hv1.y + c[2]*hv1.z + c[3]*hv1.w
                    + e[0]*hv2.x + e[1]*hv2.y + e[2]*hv2.z + e[3]*hv2.w;
        }
        #pragma unroll
        for (int m = 1; m < 64; m <<= 1)
            #pragma unroll
            for (int q = 0; q < 9; ++q) part[q] += __shfl_xor(part[q], m, 64);

        if (lane < 3) {                  // butterfly left full sums in every lane
            float dr = (lane == 0) ? part[0] : (lane == 1) ? part[3] : part[6];
            float dz = (lane == 0) ? part[1] : (lane == 1) ? part[4] : part[7];
            float dn = (lane == 0) ? part[2] : (lane == 1) ? part[5] : part[8];
            float rg = 1.f / (1.f + __expf(-(xpr + dr + blr)));
            float zg = 1.f / (1.f + __expf(-(xpz + dz + blz)));
            float ng = tanhf(xpn + rg * (dn + bln));
            float hn = (1.f - zg) * ng + zg * myh;
            myh = hn;
            unsigned hb = f2bf(hn);
            Hb[(size_t)s * EMB + b * 12 + j] = (unsigned short)hb;
            // publish: payload + tag in one atomic dword, straight to IC
            ic_store(hub + (size_t)(s + 1) * EMB + b * 12 + j, (hb << 16) | (unsigned)(s + 1));
        }
        if (s + 1 < L)
            pollh(hub + (size_t)(s + 1) * EMB + 4 * lane, (unsigned)(s + 1), hv0, hv1, hv2);
    }
}

extern "C" void kernel_launch(void* const* d_in, const int* in_sizes, int n_in,
                              void* d_out, int out_size, void* d_ws, size_t ws_size,
                              hipStream_t stream) {
    const int*   ids   = (const int*)d_in[0];
    const float* enc   = (const float*)d_in[2];
    const float* emb   = (const float*)d_in[3];
    const float* W_ih  = (const float*)d_in[4];
    const float* W_hh  = (const float*)d_in[5];
    const float* b_ih  = (const float*)d_in[6];
    const float* b_hh  = (const float*)d_in[7];
    const float* W_out = (const float*)d_in[8];
    const float* b_out = (const float*)d_in[9];
    float* out = (float*)d_out;
    const int L = out_size / VOCAB;   // 511
    if (L <= 0) return;

    // ws layout (bytes)
    char* ws = (char*)d_ws;
    unsigned short* xemb  = (unsigned short*)(ws);            // 512*768*2 = 786432
    unsigned short* Hb    = (unsigned short*)(ws + 786432);   // 512*768*2 = 786432
    float*          xproj = (float*)(ws + 1572864);           // 512*2304*4 = 4718592
    unsigned*       hub   = (unsigned*)(ws + 6291456);        // 512*768*4 = 1572864 (tagged h)
    if (ws_size < (size_t)7864320) return;

    prep_kernel<<<3, 256, 0, stream>>>(enc, hub,
        (unsigned*)(xemb + (size_t)511 * EMB), (unsigned*)(Hb + (size_t)511 * EMB));
    embed_kernel<<<L, 256, 0, stream>>>(ids, emb, xemb);
    gemm_kernel<<<(H3 + 63) / 64, 512, 0, stream>>>(xemb, W_ih, b_ih, xproj, H3, L);
    recur_kernel<<<64, 256, 0, stream>>>(W_hh, b_hh, enc, xproj, hub, Hb, L);
    gemm_kernel<<<(VOCAB + 63) / 64, 512, 0, stream>>>(Hb, W_out, b_out, out, VOCAB, L);
}